// Round 4
// baseline (105.559 us; speedup 1.0000x reference)
//
#include <hip/hip_runtime.h>
#include <math.h>

constexpr int E = 4;
constexpr int D = 32;
constexpr int K = 16;
constexpr int H = 32;

// f32 -> nearest bf16-representable f32 (RNE, matches jax/ml_dtypes cast)
__device__ __forceinline__ float bf16r(float f) {
    unsigned int u = __float_as_uint(f);
    u = (u + 0x7FFFu + ((u >> 16) & 1u)) & 0xFFFF0000u;
    return __uint_as_float(u);
}

// ---- prep: bf16-round all weight arrays into d_ws (flat f32) -------------
// layout: [0,32) rw1 | [32,64) rb1 | [64,192) rw2 | [192,196) rb2 |
//         [196,1220) wf | [1220,1732) wsp | [1732,2244) wrk | [2244,2756) wwv
__global__ void mote_prep(const float* __restrict__ r1, const float* __restrict__ b1,
                          const float* __restrict__ r2, const float* __restrict__ b2,
                          const float* __restrict__ f,  const float* __restrict__ sp,
                          const float* __restrict__ rk, const float* __restrict__ wv,
                          float* __restrict__ ws)
{
    int t = blockIdx.x * blockDim.x + threadIdx.x;
    float v;
    if      (t <   32) v = r1[t];
    else if (t <   64) v = b1[t - 32];
    else if (t <  192) v = r2[t - 64];
    else if (t <  196) v = b2[t - 192];
    else if (t < 1220) v = f [t - 196];
    else if (t < 1732) v = sp[t - 1220];
    else if (t < 2244) v = rk[t - 1732];
    else if (t < 2756) v = wv[t - 2244];
    else return;
    ws[t] = bf16r(v);
}

// ---- main: bf16-cast inputs -> f64 router/softmax/top2, f32 experts,
//            bf16-grid outputs stored as f32 ------------------------------
__global__ __launch_bounds__(256) void mote_main(
    const float* __restrict__ x_in, int B,
    const float* __restrict__ ws,
    float* __restrict__ out_emb, float* __restrict__ out_rw,
    float* __restrict__ out_mask)
{
    const int b = blockIdx.x * blockDim.x + threadIdx.x;
    if (b >= B) return;

    const float* rw1 = ws;
    const float* rb1 = ws + 32;
    const float* rw2 = ws + 64;
    const float* rb2 = ws + 192;
    const float* wf  = ws + 196;
    const float* wsp = ws + 1220;
    const float* wrk = ws + 1732;
    const float* wwv = ws + 2244;

    const float  xb = bf16r(x_in[b]);   // bf16-cast input
    const double xd = (double)xb;

    // ---------------- router MLP in f64 ----------------
    double l0 = (double)rb2[0], l1 = (double)rb2[1];
    double l2 = (double)rb2[2], l3 = (double)rb2[3];
#pragma unroll
    for (int j = 0; j < H; ++j) {
        const double h = fmax(fma(xd, (double)rw1[j], (double)rb1[j]), 0.0);
        l0 = fma(h, (double)rw2[j * E + 0], l0);
        l1 = fma(h, (double)rw2[j * E + 1], l1);
        l2 = fma(h, (double)rw2[j * E + 2], l2);
        l3 = fma(h, (double)rw2[j * E + 3], l3);
    }

    // ---------------- softmax in f64 ----------------
    double w[E];
    {
        const double mx = fmax(fmax(l0, l1), fmax(l2, l3));
        w[0] = exp(l0 - mx); w[1] = exp(l1 - mx);
        w[2] = exp(l2 - mx); w[3] = exp(l3 - mx);
        const double s = w[0] + w[1] + w[2] + w[3];
        w[0] /= s; w[1] /= s; w[2] /= s; w[3] /= s;
    }

    // ---------------- top-2, stable (lower index on ties) ----------------
    int i1 = 0;
#pragma unroll
    for (int e = 1; e < E; ++e) if (w[e] > w[i1]) i1 = e;
    int i2 = (i1 == 0) ? 1 : 0;
#pragma unroll
    for (int e = 0; e < E; ++e) if (e != i1 && w[e] > w[i2]) i2 = e;

    float dw[E] = {0.f, 0.f, 0.f, 0.f};
    float mk[E] = {0.f, 0.f, 0.f, 0.f};
    dw[i1] = (float)w[i1]; dw[i2] = (float)w[i2];
    mk[i1] = 1.0f;         mk[i2] = 1.0f;

    // small outputs (f32, bf16-grid values), coalesced 16B stores
    *reinterpret_cast<float4*>(out_rw + (size_t)E * b) =
        make_float4(bf16r((float)w[0]), bf16r((float)w[1]),
                    bf16r((float)w[2]), bf16r((float)w[3]));
    *reinterpret_cast<float4*>(out_mask + (size_t)E * b) =
        make_float4(mk[0], mk[1], mk[2], mk[3]);

    // ---------------- experts in f32 ----------------
    float4* __restrict__ orow =
        reinterpret_cast<float4*>(out_emb + (size_t)b * (E * D));
    float acc[D];

    // expert 0: fourier
    {
        float phi[2 * K];
#pragma unroll
        for (int k = 0; k < K; ++k) {
            float sn, cn;
            sincosf(xb * (float)(k + 1), &sn, &cn);
            phi[k]     = sn;
            phi[K + k] = cn;
        }
#pragma unroll
        for (int d = 0; d < D; ++d) acc[d] = 0.0f;
#pragma unroll
        for (int k = 0; k < 2 * K; ++k) {
            const float p = phi[k];
#pragma unroll
            for (int d = 0; d < D; ++d)
                acc[d] = fmaf(p, wf[k * D + d], acc[d]);
        }
#pragma unroll
        for (int q = 0; q < D / 4; ++q)
            orow[q] = make_float4(bf16r(acc[4*q+0] * dw[0]), bf16r(acc[4*q+1] * dw[0]),
                                  bf16r(acc[4*q+2] * dw[0]), bf16r(acc[4*q+3] * dw[0]));
    }

    // expert 1: spline relu(x-knot)^3
    {
        float phi[K];
#pragma unroll
        for (int k = 0; k < K; ++k) {
            const float knot = (float)(-2.0 + (double)k * (4.0 / 15.0));
            const float r = fmaxf(xb - knot, 0.0f);
            phi[k] = r * r * r;
        }
#pragma unroll
        for (int d = 0; d < D; ++d) acc[d] = 0.0f;
#pragma unroll
        for (int k = 0; k < K; ++k) {
            const float p = phi[k];
#pragma unroll
            for (int d = 0; d < D; ++d)
                acc[d] = fmaf(p, wsp[k * D + d], acc[d]);
        }
#pragma unroll
        for (int q = 0; q < D / 4; ++q)
            orow[8 + q] = make_float4(bf16r(acc[4*q+0] * dw[1]), bf16r(acc[4*q+1] * dw[1]),
                                      bf16r(acc[4*q+2] * dw[1]), bf16r(acc[4*q+3] * dw[1]));
    }

    // expert 2: rkhs gaussian exp(-4 t^2)
    {
        float phi[K];
#pragma unroll
        for (int k = 0; k < K; ++k) {
            const float knot = (float)(-2.0 + (double)k * (4.0 / 15.0));
            const float t = xb - knot;
            phi[k] = expf(-4.0f * t * t);
        }
#pragma unroll
        for (int d = 0; d < D; ++d) acc[d] = 0.0f;
#pragma unroll
        for (int k = 0; k < K; ++k) {
            const float p = phi[k];
#pragma unroll
            for (int d = 0; d < D; ++d)
                acc[d] = fmaf(p, wrk[k * D + d], acc[d]);
        }
#pragma unroll
        for (int q = 0; q < D / 4; ++q)
            orow[16 + q] = make_float4(bf16r(acc[4*q+0] * dw[2]), bf16r(acc[4*q+1] * dw[2]),
                                       bf16r(acc[4*q+2] * dw[2]), bf16r(acc[4*q+3] * dw[2]));
    }

    // expert 3: ricker wavelet (1-z^2) exp(-z^2/2), z = 2 (x - knot)
    {
        float phi[K];
#pragma unroll
        for (int k = 0; k < K; ++k) {
            const float knot = (float)(-2.0 + (double)k * (4.0 / 15.0));
            const float z  = (xb - knot) * 2.0f;
            const float z2 = z * z;
            phi[k] = (1.0f - z2) * expf(-0.5f * z2);
        }
#pragma unroll
        for (int d = 0; d < D; ++d) acc[d] = 0.0f;
#pragma unroll
        for (int k = 0; k < K; ++k) {
            const float p = phi[k];
#pragma unroll
            for (int d = 0; d < D; ++d)
                acc[d] = fmaf(p, wwv[k * D + d], acc[d]);
        }
#pragma unroll
        for (int q = 0; q < D / 4; ++q)
            orow[24 + q] = make_float4(bf16r(acc[4*q+0] * dw[3]), bf16r(acc[4*q+1] * dw[3]),
                                       bf16r(acc[4*q+2] * dw[3]), bf16r(acc[4*q+3] * dw[3]));
    }
}

extern "C" void kernel_launch(void* const* d_in, const int* in_sizes, int n_in,
                              void* d_out, int out_size, void* d_ws, size_t ws_size,
                              hipStream_t stream)
{
    const int B = in_sizes[0];   // timestamp_input (B,1) f32
    const float* x   = (const float*)d_in[0];
    const float* rw1 = (const float*)d_in[1];
    const float* rb1 = (const float*)d_in[2];
    const float* rw2 = (const float*)d_in[3];
    const float* rb2 = (const float*)d_in[4];
    const float* wf  = (const float*)d_in[5];
    const float* wsp = (const float*)d_in[6];
    const float* wrk = (const float*)d_in[7];
    const float* wwv = (const float*)d_in[8];

    float* ws = (float*)d_ws;

    // tuple layout, flat f32 (bf16-grained values) in return order:
    //   final_embedding (B*128) | raw_weights (B*4) | mask (B*4 as 1.0/0.0)
    float* out      = (float*)d_out;
    float* out_emb  = out;
    float* out_rw   = out + (size_t)B * (E * D);
    float* out_mask = out_rw + (size_t)B * E;

    hipLaunchKernelGGL(mote_prep, dim3(11), dim3(256), 0, stream,
                       rw1, rb1, rw2, rb2, wf, wsp, wrk, wwv, ws);

    const int block = 256;
    const int grid  = (B + block - 1) / block;
    hipLaunchKernelGGL(mote_main, dim3(grid), dim3(block), 0, stream,
                       x, B, ws, out_emb, out_rw, out_mask);
}

// Round 5
// 72.220 us; speedup vs baseline: 1.4616x; 1.4616x over previous
//
#include <hip/hip_runtime.h>
#include <math.h>

constexpr int E = 4;
constexpr int D = 32;
constexpr int K = 16;
constexpr int H = 32;

// f32 -> nearest bf16-representable f32 (RNE, matches jax/ml_dtypes cast)
__device__ __forceinline__ float bf16r(float f) {
    unsigned int u = __float_as_uint(f);
    u = (u + 0x7FFFu + ((u >> 16) & 1u)) & 0xFFFF0000u;
    return __uint_as_float(u);
}

// ---- prep: bf16-round all weight arrays into d_ws (flat f32) -------------
// layout: [0,32) rw1 | [32,64) rb1 | [64,192) rw2 | [192,196) rb2 |
//         [196,1220) wf | [1220,1732) wsp | [1732,2244) wrk | [2244,2756) wwv
__global__ void mote_prep(const float* __restrict__ r1, const float* __restrict__ b1,
                          const float* __restrict__ r2, const float* __restrict__ b2,
                          const float* __restrict__ f,  const float* __restrict__ sp,
                          const float* __restrict__ rk, const float* __restrict__ wv,
                          float* __restrict__ ws)
{
    int t = blockIdx.x * blockDim.x + threadIdx.x;
    float v;
    if      (t <   32) v = r1[t];
    else if (t <   64) v = b1[t - 32];
    else if (t <  192) v = r2[t - 64];
    else if (t <  196) v = b2[t - 192];
    else if (t < 1220) v = f [t - 196];
    else if (t < 1732) v = sp[t - 1220];
    else if (t < 2244) v = rk[t - 1732];
    else if (t < 2756) v = wv[t - 2244];
    else return;
    ws[t] = bf16r(v);
}

// LDS row stride: 32 f32 payload + 4 pad -> byte stride 144 (16B-aligned,
// and (row*36 + quad*4) mod 32 = 4*((row+quad)&7) spreads banks evenly for
// both the write (fixed quad, varying row) and read (8 rows x 8 quads) phases.
constexpr int LROW = 36;

// ---- main: bf16-cast inputs -> f64 router/softmax/top2, f32 experts,
//            bf16-grid outputs stored as f32 via LDS-staged full-line writes.
__global__ __launch_bounds__(256) void mote_main(
    const float* __restrict__ x_in, int B,
    const float* __restrict__ ws,
    float* __restrict__ out_emb, float* __restrict__ out_rw,
    float* __restrict__ out_mask)
{
    __shared__ float lds[256 * LROW];

    const int tid = threadIdx.x;
    const size_t blockbase = (size_t)blockIdx.x * 256;
    const int b = (int)blockbase + tid;
    const bool valid = b < B;

    const float* rw1 = ws;
    const float* rb1 = ws + 32;
    const float* rw2 = ws + 64;
    const float* rb2 = ws + 192;
    const float* wf  = ws + 196;
    const float* wsp = ws + 1220;
    const float* wrk = ws + 1732;
    const float* wwv = ws + 2244;

    const float  xb = bf16r(valid ? x_in[b] : 0.0f);   // bf16-cast input
    const double xd = (double)xb;

    // ---------------- router MLP in f64 (identical to round-4 numerics) ----
    double l0 = (double)rb2[0], l1 = (double)rb2[1];
    double l2 = (double)rb2[2], l3 = (double)rb2[3];
#pragma unroll
    for (int j = 0; j < H; ++j) {
        const double h = fmax(fma(xd, (double)rw1[j], (double)rb1[j]), 0.0);
        l0 = fma(h, (double)rw2[j * E + 0], l0);
        l1 = fma(h, (double)rw2[j * E + 1], l1);
        l2 = fma(h, (double)rw2[j * E + 2], l2);
        l3 = fma(h, (double)rw2[j * E + 3], l3);
    }

    // ---------------- softmax in f64 ----------------
    double w[E];
    {
        const double mx = fmax(fmax(l0, l1), fmax(l2, l3));
        w[0] = exp(l0 - mx); w[1] = exp(l1 - mx);
        w[2] = exp(l2 - mx); w[3] = exp(l3 - mx);
        const double s = w[0] + w[1] + w[2] + w[3];
        w[0] /= s; w[1] /= s; w[2] /= s; w[3] /= s;
    }

    // ---------------- top-2, stable (lower index on ties) ----------------
    int i1 = 0;
#pragma unroll
    for (int e = 1; e < E; ++e) if (w[e] > w[i1]) i1 = e;
    int i2 = (i1 == 0) ? 1 : 0;
#pragma unroll
    for (int e = 0; e < E; ++e) if (e != i1 && w[e] > w[i2]) i2 = e;

    float dw[E] = {0.f, 0.f, 0.f, 0.f};
    float mk[E] = {0.f, 0.f, 0.f, 0.f};
    dw[i1] = (float)w[i1]; dw[i2] = (float)w[i2];
    mk[i1] = 1.0f;         mk[i2] = 1.0f;

    // small outputs (f32 on bf16 grid), 16B contiguous per lane = full lines
    if (valid) {
        *reinterpret_cast<float4*>(out_rw + (size_t)E * b) =
            make_float4(bf16r((float)w[0]), bf16r((float)w[1]),
                        bf16r((float)w[2]), bf16r((float)w[3]));
        *reinterpret_cast<float4*>(out_mask + (size_t)E * b) =
            make_float4(mk[0], mk[1], mk[2], mk[3]);
    }

    float acc[D];

    // Stage expert chunk (weighted, rounded) to LDS, then cooperative
    // full-line global store: 8 lanes cover one row's 128B chunk.
#define STAGE_AND_STORE(EIDX, DWV)                                            \
    do {                                                                      \
        __syncthreads(); /* prior expert's LDS reads complete */              \
        _Pragma("unroll")                                                     \
        for (int q = 0; q < D / 4; ++q)                                       \
            *reinterpret_cast<float4*>(&lds[tid * LROW + q * 4]) =            \
                make_float4(bf16r(acc[4*q+0] * (DWV)), bf16r(acc[4*q+1] * (DWV)), \
                            bf16r(acc[4*q+2] * (DWV)), bf16r(acc[4*q+3] * (DWV))); \
        __syncthreads();                                                      \
        _Pragma("unroll")                                                     \
        for (int it = 0; it < 8; ++it) {                                      \
            const int idx  = it * 256 + tid;                                  \
            const int row  = idx >> 3;                                        \
            const int quad = idx & 7;                                         \
            if (blockbase + row < (size_t)B)                                  \
                *reinterpret_cast<float4*>(out_emb + (blockbase + row) * (E * D) \
                                           + (EIDX) * D + quad * 4) =         \
                    *reinterpret_cast<const float4*>(&lds[row * LROW + quad * 4]); \
        }                                                                     \
    } while (0)

    // expert 0: fourier
    {
        float phi[2 * K];
#pragma unroll
        for (int k = 0; k < K; ++k) {
            float sn, cn;
            sincosf(xb * (float)(k + 1), &sn, &cn);
            phi[k]     = sn;
            phi[K + k] = cn;
        }
#pragma unroll
        for (int d = 0; d < D; ++d) acc[d] = 0.0f;
#pragma unroll
        for (int k = 0; k < 2 * K; ++k) {
            const float p = phi[k];
#pragma unroll
            for (int d = 0; d < D; ++d)
                acc[d] = fmaf(p, wf[k * D + d], acc[d]);
        }
        STAGE_AND_STORE(0, dw[0]);
    }

    // expert 1: spline relu(x-knot)^3
    {
        float phi[K];
#pragma unroll
        for (int k = 0; k < K; ++k) {
            const float knot = (float)(-2.0 + (double)k * (4.0 / 15.0));
            const float r = fmaxf(xb - knot, 0.0f);
            phi[k] = r * r * r;
        }
#pragma unroll
        for (int d = 0; d < D; ++d) acc[d] = 0.0f;
#pragma unroll
        for (int k = 0; k < K; ++k) {
            const float p = phi[k];
#pragma unroll
            for (int d = 0; d < D; ++d)
                acc[d] = fmaf(p, wsp[k * D + d], acc[d]);
        }
        STAGE_AND_STORE(1, dw[1]);
    }

    // expert 2: rkhs gaussian exp(-4 t^2)
    {
        float phi[K];
#pragma unroll
        for (int k = 0; k < K; ++k) {
            const float knot = (float)(-2.0 + (double)k * (4.0 / 15.0));
            const float t = xb - knot;
            phi[k] = expf(-4.0f * t * t);
        }
#pragma unroll
        for (int d = 0; d < D; ++d) acc[d] = 0.0f;
#pragma unroll
        for (int k = 0; k < K; ++k) {
            const float p = phi[k];
#pragma unroll
            for (int d = 0; d < D; ++d)
                acc[d] = fmaf(p, wrk[k * D + d], acc[d]);
        }
        STAGE_AND_STORE(2, dw[2]);
    }

    // expert 3: ricker wavelet (1-z^2) exp(-z^2/2), z = 2 (x - knot)
    {
        float phi[K];
#pragma unroll
        for (int k = 0; k < K; ++k) {
            const float knot = (float)(-2.0 + (double)k * (4.0 / 15.0));
            const float z  = (xb - knot) * 2.0f;
            const float z2 = z * z;
            phi[k] = (1.0f - z2) * expf(-0.5f * z2);
        }
#pragma unroll
        for (int d = 0; d < D; ++d) acc[d] = 0.0f;
#pragma unroll
        for (int k = 0; k < K; ++k) {
            const float p = phi[k];
#pragma unroll
            for (int d = 0; d < D; ++d)
                acc[d] = fmaf(p, wwv[k * D + d], acc[d]);
        }
        STAGE_AND_STORE(3, dw[3]);
    }
#undef STAGE_AND_STORE
}

extern "C" void kernel_launch(void* const* d_in, const int* in_sizes, int n_in,
                              void* d_out, int out_size, void* d_ws, size_t ws_size,
                              hipStream_t stream)
{
    const int B = in_sizes[0];   // timestamp_input (B,1) f32
    const float* x   = (const float*)d_in[0];
    const float* rw1 = (const float*)d_in[1];
    const float* rb1 = (const float*)d_in[2];
    const float* rw2 = (const float*)d_in[3];
    const float* rb2 = (const float*)d_in[4];
    const float* wf  = (const float*)d_in[5];
    const float* wsp = (const float*)d_in[6];
    const float* wrk = (const float*)d_in[7];
    const float* wwv = (const float*)d_in[8];

    float* ws = (float*)d_ws;

    // tuple layout, flat f32 (bf16-grained values) in return order:
    //   final_embedding (B*128) | raw_weights (B*4) | mask (B*4 as 1.0/0.0)
    float* out      = (float*)d_out;
    float* out_emb  = out;
    float* out_rw   = out + (size_t)B * (E * D);
    float* out_mask = out_rw + (size_t)B * E;

    hipLaunchKernelGGL(mote_prep, dim3(11), dim3(256), 0, stream,
                       rw1, rb1, rw2, rb2, wf, wsp, wrk, wwv, ws);

    const int block = 256;
    const int grid  = (B + block - 1) / block;
    hipLaunchKernelGGL(mote_main, dim3(grid), dim3(block), 0, stream,
                       x, B, ws, out_emb, out_rw, out_mask);
}